// Round 11
// baseline (357.209 us; speedup 1.0000x reference)
//
#include <hip/hip_runtime.h>

#define NN 100000
#define NE 3200000
#define DD 128
#define NB 391                 // coarse buckets: dst>>8 (256 nodes each)
#define NCH 256                // edge chunks
#define CHUNK (NE / NCH)       // 12500
#define PSTAGE 9216            // bsort LDS staging capacity
#define SL (NN * 8)            // slice array stride in u32 (3.2 MB)

// ---------------- workspace layout ----------------
// cnt   @ 0        (int NN)      in-degree excl self loop
// start @ 400KB    (int NN)      global CSR offsets
// BT    @ 800KB    (int NB)      bucket totals
// BB    @ 804KB    (int NB)      bucket bases (atomic-cursor assigned)
// gcur  @ 808KB    (int 1)       global cursor for BB
// Wimg  @ 832KB    (u32 8192)    bf16 W^T, XOR-swizzled LDS image (32KB)
// H     @ 1MB      (int NCH*NB)  per-chunk bucket hist -> within-bucket offsets
// esrc  @ 2MB      (int NE)      src ids sorted by dst           [ends 14.8MB]
// P     @ 15MB     (u32 NE)      coarse-partitioned (src<<8)|(dst&255)
// g_s   @ 15MB     (u32 8*SL)    8 XCD-sharded slice arrays, 3.2MB each — aliases P

typedef __attribute__((ext_vector_type(8))) short bf16x8;
typedef __attribute__((ext_vector_type(4))) float f32x4;

__device__ inline unsigned bf16pair(float a, float b) {
    unsigned ua = __float_as_uint(a); ua = (ua + 0x7fffu + ((ua >> 16) & 1u)) >> 16;
    unsigned ub = __float_as_uint(b); ub = (ub + 0x7fffu + ((ub >> 16) & 1u)) >> 16;
    return ua | (ub << 16);
}
__device__ inline float bflo(unsigned u) { return __uint_as_float(u << 16); }
__device__ inline float bfhi(unsigned u) { return __uint_as_float(u & 0xffff0000u); }

// pass A: per-chunk coarse histogram (LDS) -> H[chunk][bucket].
// First 32 blocks also build the swizzled bf16 W^T image; block 0 zeroes gcur.
__global__ __launch_bounds__(256) void k_hist1(const int* __restrict__ dst, int* __restrict__ H,
                                               const float* __restrict__ W, unsigned* __restrict__ Wimg,
                                               int* __restrict__ gcur) {
    if (blockIdx.x == 0 && threadIdx.x == 0) *gcur = 0;
    if (blockIdx.x < 32) {
        int i = blockIdx.x * 256 + threadIdx.x;   // 8192 = 128 cols x 64 k-pairs
        int c = i >> 6, k2 = i & 63;
        unsigned v = bf16pair(W[(size_t)(k2 * 2) * DD + c], W[(size_t)(k2 * 2 + 1) * DD + c]);
        int byte = c * 256 + ((k2 * 4) ^ ((c & 7) << 4));
        *(unsigned*)((char*)Wimg + byte) = v;
    }
    __shared__ int h[NB];
    for (int i = threadIdx.x; i < NB; i += 256) h[i] = 0;
    __syncthreads();
    const int base = blockIdx.x * CHUNK;
    for (int i = threadIdx.x; i < CHUNK; i += 256)
        atomicAdd(&h[dst[base + i] >> 8], 1);
    __syncthreads();
    for (int i = threadIdx.x; i < NB; i += 256) H[blockIdx.x * NB + i] = h[i];
}

// pass B: per bucket, scan H column over chunks -> within-bucket chunk offsets + BT;
// BB[b] assigned via global atomic cursor (segment order run-varying; output bits unaffected).
__global__ __launch_bounds__(256) void k_offB1(int* __restrict__ H, int* __restrict__ BT,
                                               int* __restrict__ BB, int* __restrict__ gcur) {
    __shared__ int s[256];
    const int b = blockIdx.x;
    const int t = threadIdx.x;
    int v = H[t * NB + b];
    s[t] = v;
    __syncthreads();
    for (int off = 1; off < 256; off <<= 1) {
        int u = (t >= off) ? s[t - off] : 0;
        __syncthreads();
        s[t] += u;
        __syncthreads();
    }
    H[t * NB + b] = s[t] - v;
    if (t == 255) {
        BT[b] = s[255];
        BB[b] = atomicAdd(gcur, s[255]);
    }
}

// pass C: stable coarse partition, LDS cursors, zero global atomics; P packed u32
__global__ __launch_bounds__(256) void k_part(const int* __restrict__ src, const int* __restrict__ dst,
                                              const int* __restrict__ H, const int* __restrict__ BB,
                                              unsigned* __restrict__ P) {
    __shared__ int cur[NB];
    for (int i = threadIdx.x; i < NB; i += 256)
        cur[i] = BB[i] + H[blockIdx.x * NB + i];
    __syncthreads();
    const int base = blockIdx.x * CHUNK;
    for (int i = threadIdx.x; i < CHUNK; i += 256) {
        int s = src[base + i];
        int d = dst[base + i];
        int p = atomicAdd(&cur[d >> 8], 1);   // LDS atomic
        P[p] = ((unsigned)s << 8) | (unsigned)(d & 255);
    }
}

// pass D: per-bucket LDS counting sort; stages the bucket's P segment in LDS.
__global__ __launch_bounds__(256) void k_bsort(const unsigned* __restrict__ P, const int* __restrict__ BB,
                                               const int* __restrict__ BT, int* __restrict__ esrc,
                                               int* __restrict__ cnt, int* __restrict__ start) {
    __shared__ int hist[256], red[256], sexcl[256], fil[256];
    __shared__ unsigned Ps[PSTAGE];
    const int b = blockIdx.x;
    const int base = BB[b];
    const int n = BT[b];
    const int t = threadIdx.x;
    const bool fits = (n <= PSTAGE);          // block-uniform
    hist[t] = 0;
    __syncthreads();
    for (int i = t; i < n; i += 256) {
        unsigned p = P[base + i];
        if (fits) Ps[i] = p;
        atomicAdd(&hist[p & 255u], 1);
    }
    __syncthreads();
    int c = hist[t];
    red[t] = c;
    __syncthreads();
    for (int off = 1; off < 256; off <<= 1) {
        int u = (t >= off) ? red[t - off] : 0;
        __syncthreads();
        red[t] += u;
        __syncthreads();
    }
    int excl = red[t] - c;
    sexcl[t] = excl;
    fil[t] = 0;
    int node = (b << 8) + t;
    if (node < NN) { cnt[node] = c; start[node] = base + excl; }
    __syncthreads();
    for (int i = t; i < n; i += 256) {
        unsigned p = fits ? Ps[i] : P[base + i];
        int dl = (int)(p & 255u);
        int pos = atomicAdd(&fil[dl], 1);     // LDS atomic
        esrc[base + sexcl[dl] + pos] = (int)(p >> 8);
    }
}

// MFMA GEMM: g = bf16(x) @ bf16(W) * rsqrt(deg); epilogue writes XCD-sharded
// slice arrays: g_s[col>>3][row*8 + (col&7)] (col-pair index in [0,64)).
__global__ __launch_bounds__(256) void k_gemm_mfma(
    const float* __restrict__ x, const unsigned* __restrict__ Wimg,
    const int* __restrict__ cnt, unsigned* __restrict__ g_s) {
    __shared__ unsigned Wl[8192];            // 32 KB
    const int tid = threadIdx.x;
    {
        const uint4* s4 = (const uint4*)Wimg;
        uint4* d4 = (uint4*)Wl;
        for (int i = tid; i < 2048; i += 256) d4[i] = s4[i];
    }
    const int row0 = blockIdx.x * 128;
    const int w = tid >> 6;
    const int l = tid & 63;
    const int lr = l & 15, lk = l >> 4;
    bf16x8 a[2][4];
#pragma unroll
    for (int rg = 0; rg < 2; ++rg) {
        int r = row0 + w * 32 + rg * 16 + lr;
        if (r > NN - 1) r = NN - 1;
        const float* xr = x + (size_t)r * DD;
#pragma unroll
        for (int kk = 0; kk < 4; ++kk) {
            float4 f0 = *(const float4*)(xr + kk * 32 + lk * 8);
            float4 f1 = *(const float4*)(xr + kk * 32 + lk * 8 + 4);
            uint4 wv;
            wv.x = bf16pair(f0.x, f0.y); wv.y = bf16pair(f0.z, f0.w);
            wv.z = bf16pair(f1.x, f1.y); wv.w = bf16pair(f1.z, f1.w);
            a[rg][kk] = *(bf16x8*)&wv;
        }
    }
    __syncthreads();
    f32x4 acc[2][8];
#pragma unroll
    for (int rg = 0; rg < 2; ++rg)
#pragma unroll
        for (int t = 0; t < 8; ++t) acc[rg][t] = (f32x4){0.f, 0.f, 0.f, 0.f};
#pragma unroll
    for (int t = 0; t < 8; ++t) {
        int c = t * 16 + lr;
#pragma unroll
        for (int kk = 0; kk < 4; ++kk) {
            int byte = c * 256 + ((kk * 64 + lk * 16) ^ ((c & 7) << 4));
            bf16x8 bfr = *(bf16x8*)((char*)Wl + byte);
            acc[0][t] = __builtin_amdgcn_mfma_f32_16x16x32_bf16(a[0][kk], bfr, acc[0][t], 0, 0, 0);
            acc[1][t] = __builtin_amdgcn_mfma_f32_16x16x32_bf16(a[1][kk], bfr, acc[1][t], 0, 0, 0);
        }
    }
#pragma unroll
    for (int rg = 0; rg < 2; ++rg)
#pragma unroll
    for (int j = 0; j < 4; ++j) {
        int row = row0 + w * 32 + rg * 16 + lk * 4 + j;
        if (row < NN) {
            float dinv = rsqrtf((float)(cnt[row] + 1));
#pragma unroll
            for (int t = 0; t < 4; ++t) {
                int col = t * 16 + lr;                 // col-pair index 0..63
                unsigned v = bf16pair(acc[rg][t][j] * dinv, acc[rg][t + 4][j] * dinv);
                g_s[(size_t)(col >> 3) * SL + (size_t)row * 8 + (col & 7)] = v;
            }
        }
    }
}

// XCD-sharded aggregate: slice = blockIdx&7 pins each 3.2MB slice array to one XCD L2.
// Block = 4 waves = 4 nodes (one slice). Wave round = 8 edges x 8 col-pairs (unconditional);
// single guarded tail round; 3x shfl_xor folds edge slots.
__global__ __launch_bounds__(256) void k_aggregate(
    const unsigned* __restrict__ g_s, const int* __restrict__ esrc,
    const int* __restrict__ start, const int* __restrict__ cnt,
    const float* __restrict__ b, float* __restrict__ out) {
    const int slice = blockIdx.x & 7;
    const int node = (blockIdx.x >> 3) * 4 + (threadIdx.x >> 6);
    const int lane = threadIdx.x & 63;
    const int slot = lane >> 3;            // edge slot 0..7
    const int c = lane & 7;                // col-pair within slice
    const unsigned* gs = g_s + (size_t)slice * SL + c;
    float ax = 0.f, ay = 0.f;
    if (slot == 0) {                        // self term counted once
        unsigned v = gs[(unsigned)node * 8u];
        ax = bflo(v); ay = bfhi(v);
    }
    const int base = start[node];
    const int n = cnt[node];
    const int* ep = esrc + base;
    int j = 0;
    for (; j + 32 <= n; j += 32) {          // 4 rounds in flight
        unsigned v0 = gs[(unsigned)ep[j + slot] * 8u];
        unsigned v1 = gs[(unsigned)ep[j + 8 + slot] * 8u];
        unsigned v2 = gs[(unsigned)ep[j + 16 + slot] * 8u];
        unsigned v3 = gs[(unsigned)ep[j + 24 + slot] * 8u];
        ax += bflo(v0) + bflo(v1) + bflo(v2) + bflo(v3);
        ay += bfhi(v0) + bfhi(v1) + bfhi(v2) + bfhi(v3);
    }
    for (; j + 8 <= n; j += 8) {            // unconditional 8-edge rounds
        unsigned v = gs[(unsigned)ep[j + slot] * 8u];
        ax += bflo(v); ay += bfhi(v);
    }
    if (j < n && slot < n - j) {            // single guarded tail round
        unsigned v = gs[(unsigned)ep[j + slot] * 8u];
        ax += bflo(v); ay += bfhi(v);
    }
    ax += __shfl_xor(ax, 8);  ay += __shfl_xor(ay, 8);
    ax += __shfl_xor(ax, 16); ay += __shfl_xor(ay, 16);
    ax += __shfl_xor(ax, 32); ay += __shfl_xor(ay, 32);
    if (slot == 0) {
        float dinv = rsqrtf((float)(n + 1));
        int col = slice * 8 + c;
        float ox = fmaxf(fmaf(ax, dinv, b[col]), 0.f);
        float oy = fmaxf(fmaf(ay, dinv, b[col + 64]), 0.f);
        __builtin_nontemporal_store(ox, &out[(size_t)node * DD + col]);
        __builtin_nontemporal_store(oy, &out[(size_t)node * DD + col + 64]);
    }
}

extern "C" void kernel_launch(void* const* d_in, const int* in_sizes, int n_in,
                              void* d_out, int out_size, void* d_ws, size_t ws_size,
                              hipStream_t stream) {
    const float* x = (const float*)d_in[0];
    const int* edge = (const int*)d_in[1];
    const float* W = (const float*)d_in[2];
    const float* b = (const float*)d_in[3];
    float* out = (float*)d_out;

    char* ws = (char*)d_ws;
    int* cnt      = (int*)(ws);
    int* start    = (int*)(ws + 400 * 1024);
    int* BT       = (int*)(ws + 800 * 1024);
    int* BB       = (int*)(ws + 804 * 1024);
    int* gcur     = (int*)(ws + 808 * 1024);
    unsigned* Wim = (unsigned*)(ws + 832 * 1024);
    int* H        = (int*)(ws + (1 << 20));
    int* esrc     = (int*)(ws + (2 << 20));
    unsigned* P   = (unsigned*)(ws + (15ull << 20));
    unsigned* g_s = (unsigned*)(ws + (15ull << 20));   // aliases P: P dead before gemm

    const int* src = edge;        // edge_index[0]
    const int* dst = edge + NE;   // edge_index[1]

    k_hist1<<<NCH, 256, 0, stream>>>(dst, H, W, Wim, gcur);
    k_offB1<<<NB, 256, 0, stream>>>(H, BT, BB, gcur);
    k_part<<<NCH, 256, 0, stream>>>(src, dst, H, BB, P);
    k_bsort<<<NB, 256, 0, stream>>>(P, BB, BT, esrc, cnt, start);
    k_gemm_mfma<<<(NN + 127) / 128, 256, 0, stream>>>(x, Wim, cnt, g_s);
    k_aggregate<<<(NN / 4) * 8, 256, 0, stream>>>(g_s, esrc, start, cnt, b, out);
}

// Round 12
// 304.046 us; speedup vs baseline: 1.1749x; 1.1749x over previous
//
#include <hip/hip_runtime.h>

#define NN 100000
#define NE 3200000
#define DD 128
#define NB 391                 // coarse buckets: dst>>8 (256 nodes each)
#define NCH 256                // edge chunks
#define CHUNK (NE / NCH)       // 12500
#define PSTAGE 9216            // bsort LDS staging capacity (real count)
#define SL ((NN + 1) * 8)      // slice array stride in u32 (row NN = zero row)

// ---------------- workspace layout ----------------
// cnt   @ 0        (int NN)      in-degree excl self loop
// start @ 400KB    (int NN)      padded CSR offsets (segment incl self @0 + pad)
// BT    @ 800KB    (int NB)      bucket totals (real)
// BB    @ 804KB    (int NB)      bucket bases (cursor, +2048 pad reservation each)
// gcur  @ 808KB    (int 1)       global cursor for BB
// Wimg  @ 832KB    (u32 8192)    bf16 W^T, XOR-swizzled LDS image (32KB)
// H     @ 1MB      (int NCH*NB)  per-chunk bucket hist -> within-bucket offsets
// esrc  @ 2MB      (int ~4.0M)   padded edge lists [self, edges..., NN-dummies]  (16MB cap)
// P     @ 18MB     (u32 NE+gaps) coarse-partitioned (src<<8)|(dst&255)           (16MB cap)
// g_s   @ 18MB     (u32 8*SL)    8 XCD-sharded slice arrays (3.2MB each) — aliases P

typedef __attribute__((ext_vector_type(8))) short bf16x8;
typedef __attribute__((ext_vector_type(4))) float f32x4;

__device__ inline unsigned bf16pair(float a, float b) {
    unsigned ua = __float_as_uint(a); ua = (ua + 0x7fffu + ((ua >> 16) & 1u)) >> 16;
    unsigned ub = __float_as_uint(b); ub = (ub + 0x7fffu + ((ub >> 16) & 1u)) >> 16;
    return ua | (ub << 16);
}
__device__ inline float bflo(unsigned u) { return __uint_as_float(u << 16); }
__device__ inline float bfhi(unsigned u) { return __uint_as_float(u & 0xffff0000u); }

// pass A: per-chunk coarse histogram (LDS) -> H[chunk][bucket].
// First 32 blocks also build the swizzled bf16 W^T image; block 0 zeroes gcur.
__global__ __launch_bounds__(256) void k_hist1(const int* __restrict__ dst, int* __restrict__ H,
                                               const float* __restrict__ W, unsigned* __restrict__ Wimg,
                                               int* __restrict__ gcur) {
    if (blockIdx.x == 0 && threadIdx.x == 0) *gcur = 0;
    if (blockIdx.x < 32) {
        int i = blockIdx.x * 256 + threadIdx.x;   // 8192 = 128 cols x 64 k-pairs
        int c = i >> 6, k2 = i & 63;
        unsigned v = bf16pair(W[(size_t)(k2 * 2) * DD + c], W[(size_t)(k2 * 2 + 1) * DD + c]);
        int byte = c * 256 + ((k2 * 4) ^ ((c & 7) << 4));
        *(unsigned*)((char*)Wimg + byte) = v;
    }
    __shared__ int h[NB];
    for (int i = threadIdx.x; i < NB; i += 256) h[i] = 0;
    __syncthreads();
    const int base = blockIdx.x * CHUNK;
    for (int i = threadIdx.x; i < CHUNK; i += 256)
        atomicAdd(&h[dst[base + i] >> 8], 1);
    __syncthreads();
    for (int i = threadIdx.x; i < NB; i += 256) H[blockIdx.x * NB + i] = h[i];
}

// pass B: per bucket, scan H column over chunks -> within-bucket chunk offsets + BT;
// BB[b] via global cursor with +2048 reservation (room for per-node self+pad slots).
__global__ __launch_bounds__(256) void k_offB1(int* __restrict__ H, int* __restrict__ BT,
                                               int* __restrict__ BB, int* __restrict__ gcur) {
    __shared__ int s[256];
    const int b = blockIdx.x;
    const int t = threadIdx.x;
    int v = H[t * NB + b];
    s[t] = v;
    __syncthreads();
    for (int off = 1; off < 256; off <<= 1) {
        int u = (t >= off) ? s[t - off] : 0;
        __syncthreads();
        s[t] += u;
        __syncthreads();
    }
    H[t * NB + b] = s[t] - v;
    if (t == 255) {
        BT[b] = s[255];
        BB[b] = atomicAdd(gcur, s[255] + 2048);
    }
}

// pass C: stable coarse partition, LDS cursors, zero global atomics; P packed u32
__global__ __launch_bounds__(256) void k_part(const int* __restrict__ src, const int* __restrict__ dst,
                                              const int* __restrict__ H, const int* __restrict__ BB,
                                              unsigned* __restrict__ P) {
    __shared__ int cur[NB];
    for (int i = threadIdx.x; i < NB; i += 256)
        cur[i] = BB[i] + H[blockIdx.x * NB + i];
    __syncthreads();
    const int base = blockIdx.x * CHUNK;
    for (int i = threadIdx.x; i < CHUNK; i += 256) {
        int s = src[base + i];
        int d = dst[base + i];
        int p = atomicAdd(&cur[d >> 8], 1);   // LDS atomic
        P[p] = ((unsigned)s << 8) | (unsigned)(d & 255);
    }
}

// pass D: per-bucket LDS counting sort with PADDED output segments:
// node segment = [self, e0..e_{c-1}, NN-dummies] rounded up to 8. Emits esrc+cnt+start.
__global__ __launch_bounds__(256) void k_bsort(const unsigned* __restrict__ P, const int* __restrict__ BB,
                                               const int* __restrict__ BT, int* __restrict__ esrc,
                                               int* __restrict__ cnt, int* __restrict__ start) {
    __shared__ int hist[256], red[256], sexcl[256], fil[256];
    __shared__ unsigned Ps[PSTAGE];
    const int b = blockIdx.x;
    const int base = BB[b];
    const int n = BT[b];
    const int t = threadIdx.x;
    const bool fits = (n <= PSTAGE);          // block-uniform
    hist[t] = 0;
    __syncthreads();
    for (int i = t; i < n; i += 256) {
        unsigned p = P[base + i];
        if (fits) Ps[i] = p;
        atomicAdd(&hist[p & 255u], 1);
    }
    __syncthreads();
    const int node = (b << 8) + t;
    int c = hist[t];
    int pc = (node < NN) ? ((c + 8) & ~7) : 0;   // padded size incl self edge
    red[t] = pc;
    __syncthreads();
    for (int off = 1; off < 256; off <<= 1) {
        int u = (t >= off) ? red[t - off] : 0;
        __syncthreads();
        red[t] += u;
        __syncthreads();
    }
    int pexcl = red[t] - pc;
    sexcl[t] = pexcl;
    fil[t] = 0;
    if (node < NN) {
        cnt[node] = c;
        start[node] = base + pexcl;
        esrc[base + pexcl] = node;               // self edge at slot 0
        for (int i = c + 1; i < pc; ++i)         // dummies -> zero row NN
            esrc[base + pexcl + i] = NN;
    }
    __syncthreads();
    for (int i = t; i < n; i += 256) {
        unsigned p = fits ? Ps[i] : P[base + i];
        int dl = (int)(p & 255u);
        int pos = atomicAdd(&fil[dl], 1);        // LDS atomic
        esrc[base + sexcl[dl] + 1 + pos] = (int)(p >> 8);
    }
}

// MFMA GEMM: g = bf16(x) @ bf16(W) * rsqrt(deg); epilogue writes XCD-sharded
// slice arrays g_s[col>>3][row*8 + (col&7)]; row NN is written as zeros.
__global__ __launch_bounds__(256) void k_gemm_mfma(
    const float* __restrict__ x, const unsigned* __restrict__ Wimg,
    const int* __restrict__ cnt, unsigned* __restrict__ g_s) {
    __shared__ unsigned Wl[8192];            // 32 KB
    const int tid = threadIdx.x;
    {
        const uint4* s4 = (const uint4*)Wimg;
        uint4* d4 = (uint4*)Wl;
        for (int i = tid; i < 2048; i += 256) d4[i] = s4[i];
    }
    const int row0 = blockIdx.x * 128;
    const int w = tid >> 6;
    const int l = tid & 63;
    const int lr = l & 15, lk = l >> 4;
    bf16x8 a[2][4];
#pragma unroll
    for (int rg = 0; rg < 2; ++rg) {
        int r = row0 + w * 32 + rg * 16 + lr;
        if (r > NN - 1) r = NN - 1;
        const float* xr = x + (size_t)r * DD;
#pragma unroll
        for (int kk = 0; kk < 4; ++kk) {
            float4 f0 = *(const float4*)(xr + kk * 32 + lk * 8);
            float4 f1 = *(const float4*)(xr + kk * 32 + lk * 8 + 4);
            uint4 wv;
            wv.x = bf16pair(f0.x, f0.y); wv.y = bf16pair(f0.z, f0.w);
            wv.z = bf16pair(f1.x, f1.y); wv.w = bf16pair(f1.z, f1.w);
            a[rg][kk] = *(bf16x8*)&wv;
        }
    }
    __syncthreads();
    f32x4 acc[2][8];
#pragma unroll
    for (int rg = 0; rg < 2; ++rg)
#pragma unroll
        for (int t = 0; t < 8; ++t) acc[rg][t] = (f32x4){0.f, 0.f, 0.f, 0.f};
#pragma unroll
    for (int t = 0; t < 8; ++t) {
        int c = t * 16 + lr;
#pragma unroll
        for (int kk = 0; kk < 4; ++kk) {
            int byte = c * 256 + ((kk * 64 + lk * 16) ^ ((c & 7) << 4));
            bf16x8 bfr = *(bf16x8*)((char*)Wl + byte);
            acc[0][t] = __builtin_amdgcn_mfma_f32_16x16x32_bf16(a[0][kk], bfr, acc[0][t], 0, 0, 0);
            acc[1][t] = __builtin_amdgcn_mfma_f32_16x16x32_bf16(a[1][kk], bfr, acc[1][t], 0, 0, 0);
        }
    }
#pragma unroll
    for (int rg = 0; rg < 2; ++rg)
#pragma unroll
    for (int j = 0; j < 4; ++j) {
        int row = row0 + w * 32 + rg * 16 + lk * 4 + j;
        if (row < NN) {
            float dinv = rsqrtf((float)(cnt[row] + 1));
#pragma unroll
            for (int t = 0; t < 4; ++t) {
                int col = t * 16 + lr;                 // col-pair index 0..63
                unsigned v = bf16pair(acc[rg][t][j] * dinv, acc[rg][t + 4][j] * dinv);
                g_s[(size_t)(col >> 3) * SL + (size_t)row * 8 + (col & 7)] = v;
            }
        } else if (row == NN) {
#pragma unroll
            for (int t = 0; t < 4; ++t) {
                int col = t * 16 + lr;
                g_s[(size_t)(col >> 3) * SL + (size_t)NN * 8 + (col & 7)] = 0u;
            }
        }
    }
}

// XCD-sharded aggregate, fully unconditional rounds:
// slice = bid&7 pins a 3.2MB slice array per XCD L2. Wave = 8 slots x 8 cols;
// padded segment (self @0, dummies->zero row) => no guards, no tails, no self special-case.
__global__ __launch_bounds__(256) void k_aggregate(
    const unsigned* __restrict__ g_s, const int* __restrict__ esrc,
    const int* __restrict__ start, const int* __restrict__ cnt,
    const float* __restrict__ b, float* __restrict__ out) {
    const int slice = blockIdx.x & 7;
    const int node = (blockIdx.x >> 3) * 4 + (threadIdx.x >> 6);
    const int lane = threadIdx.x & 63;
    const int slot = lane >> 3;            // edge slot 0..7
    const int c = lane & 7;                // col-pair within slice
    const unsigned* gs = g_s + (size_t)slice * SL + c;
    const int n = cnt[node];
    const int* ep = esrc + start[node];
    int rounds = ((n + 8) & ~7) >> 3;      // wave-uniform; >= 1
    float ax = 0.f, ay = 0.f;
    int j = slot;
    while (rounds >= 4) {                  // 32 edges: 4 ep + 4 gathers in flight
        int e0 = ep[j], e1 = ep[j + 8], e2 = ep[j + 16], e3 = ep[j + 24];
        unsigned v0 = gs[(unsigned)e0 * 8u];
        unsigned v1 = gs[(unsigned)e1 * 8u];
        unsigned v2 = gs[(unsigned)e2 * 8u];
        unsigned v3 = gs[(unsigned)e3 * 8u];
        ax += bflo(v0) + bflo(v1) + bflo(v2) + bflo(v3);
        ay += bfhi(v0) + bfhi(v1) + bfhi(v2) + bfhi(v3);
        j += 32; rounds -= 4;
    }
    if (rounds & 2) {
        int e0 = ep[j], e1 = ep[j + 8];
        unsigned v0 = gs[(unsigned)e0 * 8u];
        unsigned v1 = gs[(unsigned)e1 * 8u];
        ax += bflo(v0) + bflo(v1); ay += bfhi(v0) + bfhi(v1);
        j += 16;
    }
    if (rounds & 1) {
        unsigned v = gs[(unsigned)ep[j] * 8u];
        ax += bflo(v); ay += bfhi(v);
    }
    ax += __shfl_xor(ax, 8);  ay += __shfl_xor(ay, 8);
    ax += __shfl_xor(ax, 16); ay += __shfl_xor(ay, 16);
    ax += __shfl_xor(ax, 32); ay += __shfl_xor(ay, 32);
    if (slot == 0) {
        float dinv = rsqrtf((float)(n + 1));
        int col = slice * 8 + c;
        float ox = fmaxf(fmaf(ax, dinv, b[col]), 0.f);
        float oy = fmaxf(fmaf(ay, dinv, b[col + 64]), 0.f);
        __builtin_nontemporal_store(ox, &out[(size_t)node * DD + col]);
        __builtin_nontemporal_store(oy, &out[(size_t)node * DD + col + 64]);
    }
}

extern "C" void kernel_launch(void* const* d_in, const int* in_sizes, int n_in,
                              void* d_out, int out_size, void* d_ws, size_t ws_size,
                              hipStream_t stream) {
    const float* x = (const float*)d_in[0];
    const int* edge = (const int*)d_in[1];
    const float* W = (const float*)d_in[2];
    const float* b = (const float*)d_in[3];
    float* out = (float*)d_out;

    char* ws = (char*)d_ws;
    int* cnt      = (int*)(ws);
    int* start    = (int*)(ws + 400 * 1024);
    int* BT       = (int*)(ws + 800 * 1024);
    int* BB       = (int*)(ws + 804 * 1024);
    int* gcur     = (int*)(ws + 808 * 1024);
    unsigned* Wim = (unsigned*)(ws + 832 * 1024);
    int* H        = (int*)(ws + (1 << 20));
    int* esrc     = (int*)(ws + (2ull << 20));
    unsigned* P   = (unsigned*)(ws + (18ull << 20));
    unsigned* g_s = (unsigned*)(ws + (18ull << 20));   // aliases P: P dead before gemm

    const int* src = edge;        // edge_index[0]
    const int* dst = edge + NE;   // edge_index[1]

    k_hist1<<<NCH, 256, 0, stream>>>(dst, H, W, Wim, gcur);
    k_offB1<<<NB, 256, 0, stream>>>(H, BT, BB, gcur);
    k_part<<<NCH, 256, 0, stream>>>(src, dst, H, BB, P);
    k_bsort<<<NB, 256, 0, stream>>>(P, BB, BT, esrc, cnt, start);
    k_gemm_mfma<<<(NN + 127) / 128, 256, 0, stream>>>(x, Wim, cnt, g_s);
    k_aggregate<<<(NN / 4) * 8, 256, 0, stream>>>(g_s, esrc, start, cnt, b, out);
}

// Round 13
// 204.140 us; speedup vs baseline: 1.7498x; 1.4894x over previous
//
#include <hip/hip_runtime.h>

#define NN 100000
#define NE 3200000
#define DD 128
#define NB 391                 // coarse buckets: dst>>8 (256 nodes each)
#define NCH 256                // edge chunks
#define CHUNK (NE / NCH)       // 12500
#define PSTAGE 9216            // bsort LDS staging capacity (real bucket count)

// ---------------- workspace layout ----------------
// cnt   @ 0        (int NN)      in-degree excl self loop
// start @ 400KB    (int NN)      padded CSR offsets (segment = [self, edges, pad])
// BT    @ 800KB    (int NB)      bucket totals (real)
// BB    @ 804KB    (int NB)      bucket bases (cursor, +4096 pad reservation)
// gcur  @ 808KB    (int 1)       global cursor for BB
// Wimg  @ 832KB    (u32 8192)    bf16 W^T, XOR-swizzled LDS image (32KB)
// H     @ 1MB      (int NCH*NB)  per-chunk bucket hist -> within-bucket offsets
// esrc  @ 2MB      (int <=4.8M)  padded edge lists [self, edges..., NN-dummies] (20MB region)
// P     @ 22MB     (u32 NE+gaps) coarse-partitioned (src<<8)|(dst&255)
// g     @ 22MB     (u32 (NN+1)*64) bf16x2 (cols i,i+64); row NN = zeros — aliases P

typedef __attribute__((ext_vector_type(8))) short bf16x8;
typedef __attribute__((ext_vector_type(4))) float f32x4;

__device__ inline unsigned bf16pair(float a, float b) {
    unsigned ua = __float_as_uint(a); ua = (ua + 0x7fffu + ((ua >> 16) & 1u)) >> 16;
    unsigned ub = __float_as_uint(b); ub = (ub + 0x7fffu + ((ub >> 16) & 1u)) >> 16;
    return ua | (ub << 16);
}
__device__ inline float bflo(unsigned u) { return __uint_as_float(u << 16); }
__device__ inline float bfhi(unsigned u) { return __uint_as_float(u & 0xffff0000u); }

// pass A: per-chunk coarse histogram (LDS) -> H[chunk][bucket].
// First 32 blocks also build the swizzled bf16 W^T image; block 0 zeroes gcur.
__global__ __launch_bounds__(256) void k_hist1(const int* __restrict__ dst, int* __restrict__ H,
                                               const float* __restrict__ W, unsigned* __restrict__ Wimg,
                                               int* __restrict__ gcur) {
    if (blockIdx.x == 0 && threadIdx.x == 0) *gcur = 0;
    if (blockIdx.x < 32) {
        int i = blockIdx.x * 256 + threadIdx.x;   // 8192 = 128 cols x 64 k-pairs
        int c = i >> 6, k2 = i & 63;
        unsigned v = bf16pair(W[(size_t)(k2 * 2) * DD + c], W[(size_t)(k2 * 2 + 1) * DD + c]);
        int byte = c * 256 + ((k2 * 4) ^ ((c & 7) << 4));
        *(unsigned*)((char*)Wimg + byte) = v;
    }
    __shared__ int h[NB];
    for (int i = threadIdx.x; i < NB; i += 256) h[i] = 0;
    __syncthreads();
    const int base = blockIdx.x * CHUNK;
    for (int i = threadIdx.x; i < CHUNK; i += 256)
        atomicAdd(&h[dst[base + i] >> 8], 1);
    __syncthreads();
    for (int i = threadIdx.x; i < NB; i += 256) H[blockIdx.x * NB + i] = h[i];
}

// pass B: per bucket, scan H column over chunks -> within-bucket chunk offsets + BT;
// BB[b] via global cursor with +4096 reservation (self + pad-to-16 slots per node).
__global__ __launch_bounds__(256) void k_offB1(int* __restrict__ H, int* __restrict__ BT,
                                               int* __restrict__ BB, int* __restrict__ gcur) {
    __shared__ int s[256];
    const int b = blockIdx.x;
    const int t = threadIdx.x;
    int v = H[t * NB + b];
    s[t] = v;
    __syncthreads();
    for (int off = 1; off < 256; off <<= 1) {
        int u = (t >= off) ? s[t - off] : 0;
        __syncthreads();
        s[t] += u;
        __syncthreads();
    }
    H[t * NB + b] = s[t] - v;
    if (t == 255) {
        BT[b] = s[255];
        BB[b] = atomicAdd(gcur, s[255] + 4096);
    }
}

// pass C: stable coarse partition, LDS cursors, zero global atomics; P packed u32
__global__ __launch_bounds__(256) void k_part(const int* __restrict__ src, const int* __restrict__ dst,
                                              const int* __restrict__ H, const int* __restrict__ BB,
                                              unsigned* __restrict__ P) {
    __shared__ int cur[NB];
    for (int i = threadIdx.x; i < NB; i += 256)
        cur[i] = BB[i] + H[blockIdx.x * NB + i];
    __syncthreads();
    const int base = blockIdx.x * CHUNK;
    for (int i = threadIdx.x; i < CHUNK; i += 256) {
        int s = src[base + i];
        int d = dst[base + i];
        int p = atomicAdd(&cur[d >> 8], 1);   // LDS atomic
        P[p] = ((unsigned)s << 8) | (unsigned)(d & 255);
    }
}

// pass D: per-bucket LDS counting sort with PADDED segments:
// node segment = [self, e0..e_{c-1}, NN-dummies] rounded up to 16. Emits esrc+cnt+start.
__global__ __launch_bounds__(256) void k_bsort(const unsigned* __restrict__ P, const int* __restrict__ BB,
                                               const int* __restrict__ BT, int* __restrict__ esrc,
                                               int* __restrict__ cnt, int* __restrict__ start) {
    __shared__ int hist[256], red[256], sexcl[256], fil[256];
    __shared__ unsigned Ps[PSTAGE];
    const int b = blockIdx.x;
    const int base = BB[b];
    const int n = BT[b];
    const int t = threadIdx.x;
    const bool fits = (n <= PSTAGE);          // block-uniform
    hist[t] = 0;
    __syncthreads();
    for (int i = t; i < n; i += 256) {
        unsigned p = P[base + i];
        if (fits) Ps[i] = p;
        atomicAdd(&hist[p & 255u], 1);
    }
    __syncthreads();
    const int node = (b << 8) + t;
    int c = hist[t];
    int pc = (node < NN) ? ((c + 16) & ~15) : 0;   // 1 self + c edges, pad to x16
    red[t] = pc;
    __syncthreads();
    for (int off = 1; off < 256; off <<= 1) {
        int u = (t >= off) ? red[t - off] : 0;
        __syncthreads();
        red[t] += u;
        __syncthreads();
    }
    int pexcl = red[t] - pc;
    sexcl[t] = pexcl;
    fil[t] = 0;
    if (node < NN) {
        cnt[node] = c;
        start[node] = base + pexcl;
        esrc[base + pexcl] = node;               // self edge at slot 0
        for (int i = c + 1; i < pc; ++i)         // dummies -> zero row NN
            esrc[base + pexcl + i] = NN;
    }
    __syncthreads();
    for (int i = t; i < n; i += 256) {
        unsigned p = fits ? Ps[i] : P[base + i];
        int dl = (int)(p & 255u);
        int pos = atomicAdd(&fil[dl], 1);        // LDS atomic
        esrc[base + sexcl[dl] + 1 + pos] = (int)(p >> 8);
    }
}

// MFMA GEMM: g = bf16(x) @ bf16(W) * rsqrt(deg), packed (col i, i+64) pairs.
// 128 rows/block; A-fragments direct from global x; W in LDS. Row NN written as zeros.
__global__ __launch_bounds__(256) void k_gemm_mfma(
    const float* __restrict__ x, const unsigned* __restrict__ Wimg,
    const int* __restrict__ cnt, unsigned* __restrict__ g) {
    __shared__ unsigned Wl[8192];            // 32 KB
    const int tid = threadIdx.x;
    {
        const uint4* s4 = (const uint4*)Wimg;
        uint4* d4 = (uint4*)Wl;
        for (int i = tid; i < 2048; i += 256) d4[i] = s4[i];
    }
    const int row0 = blockIdx.x * 128;
    const int w = tid >> 6;
    const int l = tid & 63;
    const int lr = l & 15, lk = l >> 4;
    bf16x8 a[2][4];
#pragma unroll
    for (int rg = 0; rg < 2; ++rg) {
        int r = row0 + w * 32 + rg * 16 + lr;
        if (r > NN - 1) r = NN - 1;
        const float* xr = x + (size_t)r * DD;
#pragma unroll
        for (int kk = 0; kk < 4; ++kk) {
            float4 f0 = *(const float4*)(xr + kk * 32 + lk * 8);
            float4 f1 = *(const float4*)(xr + kk * 32 + lk * 8 + 4);
            uint4 wv;
            wv.x = bf16pair(f0.x, f0.y); wv.y = bf16pair(f0.z, f0.w);
            wv.z = bf16pair(f1.x, f1.y); wv.w = bf16pair(f1.z, f1.w);
            a[rg][kk] = *(bf16x8*)&wv;
        }
    }
    __syncthreads();
    f32x4 acc[2][8];
#pragma unroll
    for (int rg = 0; rg < 2; ++rg)
#pragma unroll
        for (int t = 0; t < 8; ++t) acc[rg][t] = (f32x4){0.f, 0.f, 0.f, 0.f};
#pragma unroll
    for (int t = 0; t < 8; ++t) {
        int c = t * 16 + lr;
#pragma unroll
        for (int kk = 0; kk < 4; ++kk) {
            int byte = c * 256 + ((kk * 64 + lk * 16) ^ ((c & 7) << 4));
            bf16x8 bfr = *(bf16x8*)((char*)Wl + byte);
            acc[0][t] = __builtin_amdgcn_mfma_f32_16x16x32_bf16(a[0][kk], bfr, acc[0][t], 0, 0, 0);
            acc[1][t] = __builtin_amdgcn_mfma_f32_16x16x32_bf16(a[1][kk], bfr, acc[1][t], 0, 0, 0);
        }
    }
#pragma unroll
    for (int rg = 0; rg < 2; ++rg)
#pragma unroll
    for (int j = 0; j < 4; ++j) {
        int row = row0 + w * 32 + rg * 16 + lk * 4 + j;
        if (row < NN) {
            float dinv = rsqrtf((float)(cnt[row] + 1));
#pragma unroll
            for (int t = 0; t < 4; ++t) {
                unsigned v = bf16pair(acc[rg][t][j] * dinv, acc[rg][t + 4][j] * dinv);
                g[(size_t)row * 64 + t * 16 + lr] = v;
            }
        } else if (row == NN) {
#pragma unroll
            for (int t = 0; t < 4; ++t)
                g[(size_t)NN * 64 + t * 16 + lr] = 0u;
        }
    }
}

// one wave per dst node; lane i owns cols (i, i+64). Padded segment (self @0,
// dummies->zero row) => fully unconditional 32/16-wide batches, 32 loads in flight.
__global__ __launch_bounds__(256) void k_aggregate(
    const unsigned* __restrict__ g, const int* __restrict__ esrc,
    const int* __restrict__ start, const int* __restrict__ cnt,
    const float* __restrict__ b, float* __restrict__ out) {
    int node = blockIdx.x * 4 + (threadIdx.x >> 6);
    if (node >= NN) return;
    int lane = threadIdx.x & 63;
    const int n = cnt[node];
    const int pc = (n + 16) & ~15;          // padded segment length (incl self)
    const int* ep = esrc + start[node];
    float ax = 0.f, ay = 0.f;
    int j = 0;
    for (; j + 32 <= pc; j += 32) {         // 32 gathers issued before first consume
        unsigned va[16], vb[16];
#pragma unroll
        for (int u = 0; u < 16; ++u) va[u] = g[(unsigned)ep[j + u] * 64u + lane];
#pragma unroll
        for (int u = 0; u < 16; ++u) vb[u] = g[(unsigned)ep[j + 16 + u] * 64u + lane];
#pragma unroll
        for (int u = 0; u < 16; ++u) { ax += bflo(va[u]); ay += bfhi(va[u]); }
#pragma unroll
        for (int u = 0; u < 16; ++u) { ax += bflo(vb[u]); ay += bfhi(vb[u]); }
    }
    if (j < pc) {                            // exactly one trailing 16-batch (pc % 32 == 16)
        unsigned va[16];
#pragma unroll
        for (int u = 0; u < 16; ++u) va[u] = g[(unsigned)ep[j + u] * 64u + lane];
#pragma unroll
        for (int u = 0; u < 16; ++u) { ax += bflo(va[u]); ay += bfhi(va[u]); }
    }
    float dinv = rsqrtf((float)(n + 1));
    float bx = b[lane], by = b[lane + 64];
    float ox = fmaxf(fmaf(ax, dinv, bx), 0.f);
    float oy = fmaxf(fmaf(ay, dinv, by), 0.f);
    __builtin_nontemporal_store(ox, &out[(size_t)node * DD + lane]);
    __builtin_nontemporal_store(oy, &out[(size_t)node * DD + lane + 64]);
}

extern "C" void kernel_launch(void* const* d_in, const int* in_sizes, int n_in,
                              void* d_out, int out_size, void* d_ws, size_t ws_size,
                              hipStream_t stream) {
    const float* x = (const float*)d_in[0];
    const int* edge = (const int*)d_in[1];
    const float* W = (const float*)d_in[2];
    const float* b = (const float*)d_in[3];
    float* out = (float*)d_out;

    char* ws = (char*)d_ws;
    int* cnt      = (int*)(ws);
    int* start    = (int*)(ws + 400 * 1024);
    int* BT       = (int*)(ws + 800 * 1024);
    int* BB       = (int*)(ws + 804 * 1024);
    int* gcur     = (int*)(ws + 808 * 1024);
    unsigned* Wim = (unsigned*)(ws + 832 * 1024);
    int* H        = (int*)(ws + (1 << 20));
    int* esrc     = (int*)(ws + (2ull << 20));
    unsigned* P   = (unsigned*)(ws + (22ull << 20));
    unsigned* g   = (unsigned*)(ws + (22ull << 20));   // aliases P: P dead before gemm

    const int* src = edge;        // edge_index[0]
    const int* dst = edge + NE;   // edge_index[1]

    k_hist1<<<NCH, 256, 0, stream>>>(dst, H, W, Wim, gcur);
    k_offB1<<<NB, 256, 0, stream>>>(H, BT, BB, gcur);
    k_part<<<NCH, 256, 0, stream>>>(src, dst, H, BB, P);
    k_bsort<<<NB, 256, 0, stream>>>(P, BB, BT, esrc, cnt, start);
    k_gemm_mfma<<<(NN + 127) / 128, 256, 0, stream>>>(x, Wim, cnt, g);
    k_aggregate<<<(NN + 3) / 4, 256, 0, stream>>>(g, esrc, start, cnt, b, out);
}